// Round 8
// baseline (7629.269 us; speedup 1.0000x reference)
//
#include <hip/hip_runtime.h>
#include <math.h>

#define Bq   16
#define Tq   1024
#define INq  64
#define OUTq 64
#define Hq   512
#define Nq   128
#define Mq   40
#define SP   580      // inp row stride (floats): x[0,64) h[64,576)
#define NWGATE 128
#define NWMEM  16
#define NWG    144
#define NT     512
#define EPSq 1e-8f

typedef unsigned long long ull;

__device__ __forceinline__ float sigmf(float x){ return 1.f/(1.f + expf(-x)); }
__device__ __forceinline__ float softplusf(float x){ return (x > 20.f) ? x : log1pf(expf(x)); }

// IC-direct 64-bit tagged words: (tag<<32)|float_bits in ONE atomic word.
__device__ __forceinline__ ull icld64(const ull* p){
  return __hip_atomic_load(p, __ATOMIC_RELAXED, __HIP_MEMORY_SCOPE_AGENT);
}
__device__ __forceinline__ void icst64(ull* p, ull v){
  __hip_atomic_store(p, v, __ATOMIC_RELAXED, __HIP_MEMORY_SCOPE_AGENT);
}
__device__ __forceinline__ ull packtv(unsigned tag, float v){
  return ((ull)tag << 32) | (ull)__float_as_uint(v);
}
__device__ __forceinline__ float lowf(ull v){ return __uint_as_float((unsigned)v); }

extern "C" __global__ void __launch_bounds__(NT, 1)
ntm_kernel(const float* __restrict__ xg,  const float* __restrict__ h0g,
           const float* __restrict__ c0g, const float* __restrict__ mem0g,
           const float* __restrict__ read0g,
           const float* __restrict__ Wih, const float* __restrict__ bih,
           const float* __restrict__ Whh, const float* __restrict__ bhh,
           const float* __restrict__ Wfc, const float* __restrict__ bfc,
           const float* __restrict__ We,  const float* __restrict__ be,
           const float* __restrict__ Wa,  const float* __restrict__ ba,
           const float* __restrict__ Wk,  const float* __restrict__ bk,
           const float* __restrict__ Wb,  const float* __restrict__ bbeta,
           float* __restrict__ yout, ull* __restrict__ h_tag,
           ull* __restrict__ r_rep, ull* __restrict__ h_okr,
           ull* __restrict__ r_flag)
{
  const int wg  = blockIdx.x;
  const int tid = threadIdx.x;
  __shared__ __align__(16) char smem[60992];

  if (wg < NWGATE){
    // ------- gate WG: owns h-indices [wg*4, wg*4+4) => 16 gate rows -------
    float* inp_s  = (float*)smem;               // 16 x 580 (x | h)
    float* red_s  = (float*)(smem + 37120);     // [out*17 + kseg], 4352 floats
    float* r_s    = (float*)(smem + 54528);     // 16 x 44
    float* gate_s = (float*)(smem + 57344);     // [b*16 + l]
    float* c_s    = (float*)(smem + 58368);     // [hh*16 + b]
    float* bias_s = (float*)(smem + 58624);     // 16
    float* ored_s = (float*)(smem + 58688);     // 16 x 36

    const int kseg = tid & 15;         // k-slice: 36 floats (576 = 16*36)
    const int rg   = (tid >> 4) & 3;   // h-unit; rows l = g*4+rg
    const int bg   = tid >> 6;         // batches 2*bg, 2*bg+1
    const int rep  = wg & 7;           // which replica this WG polls

    // persistent weights: 4 rows x 36 k
    float4 w4[36];
    #pragma unroll
    for (int g = 0; g < 4; ++g){
      const int row = g*Hq + wg*4 + rg;
      #pragma unroll
      for (int kk = 0; kk < 9; ++kk){
        float v[4];
        #pragma unroll
        for (int c4 = 0; c4 < 4; ++c4){
          const int k = kseg*36 + kk*4 + c4;
          v[c4] = (k < 64) ? Wih[row*104 + k] : Whh[row*512 + (k - 64)];
        }
        w4[g*9 + kk] = make_float4(v[0], v[1], v[2], v[3]);
      }
    }
    float4 wr[10];                     // r-slice weights (finalize threads)
    if (tid < 256){
      const int l = tid & 15;
      const int row = (l >> 2)*Hq + wg*4 + (l & 3);
      const float* wir = Wih + row*104 + 64;
      #pragma unroll
      for (int q = 0; q < 10; ++q) wr[q] = *(const float4*)&wir[q*4];
    }
    float4 wf[4]; float bfcv = 0.f;    // out-column weights (wg<64)
    if (wg < 64){
      const int ks = tid & 31;
      #pragma unroll
      for (int q = 0; q < 4; ++q)
        wf[q] = *(const float4*)&Wfc[wg*Hq + ks*16 + q*4];
      bfcv = bfc[wg];
    }
    if (tid < 16){
      const int row = (tid >> 2)*Hq + wg*4 + (tid & 3);
      bias_s[tid] = bih[row] + bhh[row];
    }
    if (tid < 64){ const int hh = tid & 3, b = tid >> 2;
      c_s[hh*16 + b] = c0g[b*Hq + wg*4 + hh]; }
    { // stage x(0), h(-1)=h0 (pristine inputs: plain loads)
      const float4* x4 = (const float4*)xg;
      if (tid < 256){ const int b = tid >> 4, q = tid & 15;
        *(float4*)&inp_s[b*SP + q*4] = x4[(b*Tq + 0)*16 + q]; }
      const float4* h4 = (const float4*)h0g;
      #pragma unroll
      for (int j = 0; j < 4; ++j){ const int i4 = tid + 512*j;
        const int b = i4 >> 7, q = i4 & 127;
        *(float4*)&inp_s[b*SP + 64 + q*4] = h4[b*128 + q]; }
    }
    __syncthreads();

    for (int t = 0; t < Tq; ++t){
      // ---- GEMV(t) on staged {x(t), h(t-1)}: overlaps mem WGs' phase ----
      {
        float acc[4][2] = {};
        const float* base = inp_s + kseg*36;
        #pragma unroll
        for (int bl = 0; bl < 2; ++bl){
          const float* bp = base + (2*bg + bl)*SP;
          #pragma unroll
          for (int kk = 0; kk < 9; ++kk){
            const float4 f = *(const float4*)&bp[kk*4];
            #pragma unroll
            for (int g = 0; g < 4; ++g){
              acc[g][bl] += w4[g*9+kk].x*f.x + w4[g*9+kk].y*f.y
                          + w4[g*9+kk].z*f.z + w4[g*9+kk].w*f.w;
            }
          }
        }
        #pragma unroll
        for (int bl = 0; bl < 2; ++bl)
          #pragma unroll
          for (int g = 0; g < 4; ++g)
            red_s[((2*bg + bl)*16 + g*4 + rg)*17 + kseg] = acc[g][bl];
      }
      __syncthreads();                                 // A: red_s ready
      // ---- partial reduce (no r dependency) ----
      float part = 0.f;
      if (tid < 256){
        part = bias_s[tid & 15];
        const float* rp = &red_s[tid*17];
        #pragma unroll
        for (int j = 0; j < 16; ++j) part += rp[j];
      }
      // ---- acquire r(t-1): narrow flag poll, then ONE verified load ----
      if (t == 0){
        if (tid < 320){ const int b = tid/20, mp = tid - b*20;
          *(float2*)&r_s[b*44 + mp*2] = *(const float2*)&read0g[b*40 + mp*2]; }
      } else {
        const unsigned want = (unsigned)t;            // (t-1)+1
        if (tid < 16){                                // 16 lanes poll 16 hint flags
          const ull* fp = &r_flag[(ull)(rep*2 + ((t-1)&1))*16 + tid];
          while ((unsigned)(icld64(fp) >> 32) < want)
            __builtin_amdgcn_s_sleep(2);
        }
        __syncthreads();                              // B0: flags seen
        if (tid < 320){                               // one-shot tagged load + verify
          const ull* rt = r_rep + (ull)(rep*2 + ((t-1)&1))*640;
          ull v1 = icld64(&rt[tid]);
          ull v2 = icld64(&rt[tid + 320]);
          while (((unsigned)(v1 >> 32) != want) | ((unsigned)(v2 >> 32) != want)){
            __builtin_amdgcn_s_sleep(1);
            if ((unsigned)(v1 >> 32) != want) v1 = icld64(&rt[tid]);
            if ((unsigned)(v2 >> 32) != want) v2 = icld64(&rt[tid + 320]);
          }
          { const int b = tid/40, m = tid - b*40;           r_s[b*44 + m] = lowf(v1); }
          { const int w = tid + 320, b = w/40, m = w - b*40; r_s[b*44 + m] = lowf(v2); }
        }
      }
      __syncthreads();                                 // B1: r_s ready
      if (tid < 256){
        const int fb = tid >> 4;
        float s = part;
        #pragma unroll
        for (int q = 0; q < 10; ++q){
          const float4 rv = *(const float4*)&r_s[fb*44 + q*4];
          s += wr[q].x*rv.x + wr[q].y*rv.y + wr[q].z*rv.z + wr[q].w*rv.w;
        }
        gate_s[fb*16 + (tid & 15)] = s;
      }
      __syncthreads();                                 // C: gate_s ready
      if (tid < 64){
        const int hh = tid & 3, b = tid >> 2;
        const float gi = gate_s[b*16 + hh];
        const float gf = gate_s[b*16 + 4 + hh];
        const float gc = gate_s[b*16 + 8 + hh];
        const float go = gate_s[b*16 + 12 + hh];
        const float iv = sigmf(gi), fv = sigmf(gf), gv = tanhf(gc), ov = sigmf(go);
        const float cn = fv*c_s[hh*16 + b] + iv*gv;
        const float hn = ov*tanhf(cn);
        c_s[hh*16 + b] = cn;
        icst64(&h_tag[((ull)((t&1)*16 + b))*512 + wg*4 + hh],
               packtv((unsigned)(t+1), hn));
        if (t == Tq - 1){
          yout[Bq*Tq*OUTq + b*Hq + wg*4 + hh] = hn;              // final h
          yout[Bq*Tq*OUTq + Bq*Hq + b*Hq + wg*4 + hh] = cn;      // final c
        }
      }
      // ---- out(t-1) partials from still-staged h(t-1) (off critical path) ----
      if (wg < 64 && t > 0){
        const int ob = tid >> 5, ks = tid & 31;
        float p = 0.f;
        const float* hp = &inp_s[ob*SP + 64 + ks*16];
        #pragma unroll
        for (int q = 0; q < 4; ++q){
          const float4 f = *(const float4*)&hp[q*4];
          p += wf[q].x*f.x + wf[q].y*f.y + wf[q].z*f.z + wf[q].w*f.w;
        }
        ored_s[ob*36 + ks] = p;
      }
      // ---- h(t): poll own replica flag, then ONE bulk load (mem-verified) ----
      {
        const unsigned want = (unsigned)(t+1);
        if (tid < 16){
          const ull* fp = &h_okr[(ull)(rep*2 + (t&1))*16 + tid];
          while ((unsigned)(icld64(fp) >> 32) < want)
            __builtin_amdgcn_s_sleep(2);
        }
        __syncthreads();                               // flags ok; ored_s ready
        const ull* ht = h_tag + (ull)(t&1)*8192;
        ull v[16];
        #pragma unroll
        for (int j = 0; j < 16; ++j) v[j] = icld64(&ht[tid + 512*j]);
        if (wg < 64 && t > 0 && tid < 16){             // out(t-1) reduce in load shadow
          const float* op = &ored_s[tid*36];
          float s = bfcv;
          #pragma unroll
          for (int j = 0; j < 32; ++j) s += op[j];
          yout[(tid*Tq + (t-1))*OUTq + wg] = tanhf(s);
        }
        #pragma unroll
        for (int j = 0; j < 16; ++j)
          inp_s[j*SP + 64 + tid] = lowf(v[j]);         // b=j, dim=tid
      }
      if (t + 1 < Tq && tid < 256){                    // stage x(t+1)
        const float4* x4 = (const float4*)xg;
        const int b = tid >> 4, q = tid & 15;
        *(float4*)&inp_s[b*SP + q*4] = x4[(b*Tq + (t + 1))*16 + q];
      }
      __syncthreads();                                 // E: inp_s ready
    }
    // ---- out(1023) after the loop (h(1023) staged in inp_s) ----
    if (wg < 64){
      const int ob = tid >> 5, ks = tid & 31;
      float p = 0.f;
      const float* hp = &inp_s[ob*SP + 64 + ks*16];
      #pragma unroll
      for (int q = 0; q < 4; ++q){
        const float4 f = *(const float4*)&hp[q*4];
        p += wf[q].x*f.x + wf[q].y*f.y + wf[q].z*f.z + wf[q].w*f.w;
      }
      ored_s[ob*36 + ks] = p;
      __syncthreads();
      if (tid < 16){
        const float* op = &ored_s[tid*36];
        float s = bfcv;
        #pragma unroll
        for (int j = 0; j < 32; ++j) s += op[j];
        yout[(tid*Tq + (Tq-1))*OUTq + wg] = tanhf(s);
      }
    }
  }
  else {
    // ---------------- memory workgroup: owns batch bat ----------------
    const int bat = wg - NWGATE;
    float* mem_s  = (float*)smem;               // 128 x 44
    float* h_s    = (float*)(smem + 22528);     // 512
    float* hred_s = (float*)(smem + 24576);     // 128 x 4
    float* key_s  = (float*)(smem + 26624);     // 40
    float* e_s    = (float*)(smem + 26784);     // 40
    float* a_s    = (float*)(smem + 26944);     // 40
    float* w_s    = (float*)(smem + 27104);     // 128
    float* rred_s = (float*)(smem + 27616);     // 40 x 9

    #pragma unroll
    for (int j = 0; j < 10; ++j){
      const int e = j*512 + tid;
      const int n = e / 40, m = e - n*40;
      mem_s[n*44 + m] = mem0g[bat*(Nq*Mq) + e];
    }
    const int o  = tid & 127;          // output index (121 live)
    const int kc = tid >> 7;           // k-chunk of 128 dims (4 chunks)
    const float* wrow = (o < 40) ? (Wk + o*Hq)
                      : (o < 80) ? (We + (o-40)*Hq)
                      : (o < 120) ? (Wa + (o-80)*Hq)
                      : (o == 120) ? Wb : nullptr;
    float4 wv2[32];
    if (wrow){
      #pragma unroll
      for (int kk = 0; kk < 32; ++kk)
        wv2[kk] = *(const float4*)&wrow[kc*128 + kk*4];
    } else {
      #pragma unroll
      for (int kk = 0; kk < 32; ++kk) wv2[kk] = make_float4(0.f,0.f,0.f,0.f);
    }
    float hb0 = 0.f, hb1 = 0.f;
    if (tid < 64){
      const int o0 = tid, o1 = tid + 64;
      hb0 = (o0 < 40) ? bk[o0] : be[o0-40];
      hb1 = (o1 < 80) ? be[o1-40] : (o1 < 120) ? ba[o1-80]
          : (o1 == 120) ? bbeta[0] : 0.f;
    }
    __syncthreads();

    for (int t = 0; t < Tq; ++t){
      const int p = t & 1;
      const unsigned want = (unsigned)(t+1);
      { // poll h(t) tagged -> h_s (512 words, own batch only; 1 reader/word)
        const ull* ht = h_tag + ((ull)(p*16 + bat))*512;
        ull v;
        do { v = icld64(&ht[tid]); } while ((unsigned)(v >> 32) != want);
        h_s[tid] = lowf(v);
      }
      __syncthreads();                                 // M1
      if (tid < 8)                                     // publish h_ok replicas
        icst64(&h_okr[(ull)(tid*2 + p)*16 + bat], packtv(want, 0.f));
      { // heads GEMV: 1 output x 4 k-chunks per thread
        float a0 = 0.f;
        const float* hp = h_s + kc*128;
        #pragma unroll
        for (int kk = 0; kk < 32; ++kk){
          const float4 f = *(const float4*)&hp[kk*4];
          a0 += wv2[kk].x*f.x + wv2[kk].y*f.y + wv2[kk].z*f.z + wv2[kk].w*f.w;
        }
        hred_s[o*4 + kc] = a0;
      }
      __syncthreads();                                 // M2
      if (tid < 64){ // wave 0: serial section, shuffle-reduced
        const int l = tid;
        const float4 p0 = *(const float4*)&hred_s[l*4];
        const float4 p1 = *(const float4*)&hred_s[(l+64)*4];
        float s0 = hb0 + p0.x + p0.y + p0.z + p0.w;
        float s1 = hb1 + p1.x + p1.y + p1.z + p1.w;
        float kv = 0.f;
        if (l < 40){ kv = tanhf(s0); key_s[l] = kv; }
        else        { e_s[l-40] = sigmf(s0); }
        if (l < 16)      e_s[l+24]  = sigmf(s1);   // o1 in [64,80)
        else if (l < 56) a_s[l-16]  = tanhf(s1);   // o1 in [80,120)
        float bval = softplusf(s1) + EPSq;          // lane 56: o1==120
        const float bet = __shfl(bval, 56);
        float ss = kv*kv;
        #pragma unroll
        for (int off = 32; off; off >>= 1) ss += __shfl_xor(ss, off);
        const float rinv = 1.f/(sqrtf(ss) + EPSq);
        float sc[2];
        #pragma unroll
        for (int half = 0; half < 2; ++half){
          const int n = l + 64*half;
          float qq = 0.f, dd = 0.f;
          const float* mrow = &mem_s[n*44];
          #pragma unroll
          for (int q = 0; q < 10; ++q){
            const float4 mv = *(const float4*)&mrow[q*4];
            const float4 kvv = *(const float4*)&key_s[q*4];
            qq += mv.x*mv.x + mv.y*mv.y + mv.z*mv.z + mv.w*mv.w;
            dd += mv.x*kvv.x + mv.y*kvv.y + mv.z*kvv.z + mv.w*kvv.w;
          }
          sc[half] = bet * dd * rinv / (sqrtf(qq) + EPSq);
        }
        float mx = fmaxf(sc[0], sc[1]);
        #pragma unroll
        for (int off = 32; off; off >>= 1) mx = fmaxf(mx, __shfl_xor(mx, off));
        const float e0 = expf(sc[0] - mx), e1 = expf(sc[1] - mx);
        float sm = e0 + e1;
        #pragma unroll
        for (int off = 32; off; off >>= 1) sm += __shfl_xor(sm, off);
        const float inv = 1.f/sm;
        w_s[l] = e0*inv; w_s[l+64] = e1*inv;
      }
      __syncthreads();                                 // M3
      if (tid < 320){ // fused erase/add update + read partials
        const int m = tid % 40, ng = tid / 40;
        const float ev = e_s[m], av = a_s[m];
        float part = 0.f;
        #pragma unroll
        for (int j = 0; j < 16; ++j){
          const int n = ng*16 + j, idx = n*44 + m;
          const float mv = mem_s[idx];
          const float wn = w_s[n];
          const float nv = fmaf(wn, fmaf(-ev, mv, av), mv);
          mem_s[idx] = nv;
          part = fmaf(wn, nv, part);
        }
        rred_s[m*9 + ng] = part;
      }
      __syncthreads();                                 // M4
      if (tid < 40){
        float r = 0.f;
        #pragma unroll
        for (int j = 0; j < 8; ++j) r += rred_s[tid*9 + j];
        const ull pv = packtv(want, r);
        #pragma unroll
        for (int rp2 = 0; rp2 < 8; ++rp2)
          icst64(&r_rep[(ull)(rp2*2 + p)*640 + bat*40 + tid], pv);
      }
      if (tid < 8)                                     // hint flags (issue-ordered
        icst64(&r_flag[(ull)(tid*2 + p)*16 + bat],     //  after data; tags guard)
               packtv(want, 0.f));
    }
  }
}

extern "C" void kernel_launch(void* const* d_in, const int* in_sizes, int n_in,
                              void* d_out, int out_size, void* d_ws, size_t ws_size,
                              hipStream_t stream){
  const float* xg    = (const float*)d_in[0];
  const float* h0g   = (const float*)d_in[1];
  const float* c0g   = (const float*)d_in[2];
  const float* mem0g = (const float*)d_in[3];
  const float* read0g= (const float*)d_in[4];
  const float* Wih   = (const float*)d_in[5];
  const float* bih   = (const float*)d_in[6];
  const float* Whh   = (const float*)d_in[7];
  const float* bhh   = (const float*)d_in[8];
  const float* Wfc   = (const float*)d_in[9];
  const float* bfc   = (const float*)d_in[10];
  const float* We    = (const float*)d_in[11];
  const float* be    = (const float*)d_in[12];
  const float* Wa    = (const float*)d_in[13];
  const float* ba    = (const float*)d_in[14];
  const float* Wk    = (const float*)d_in[15];
  const float* bk    = (const float*)d_in[16];
  const float* Wb    = (const float*)d_in[17];
  const float* bbeta = (const float*)d_in[18];

  float* yout  = (float*)d_out;
  ull*   h_tag  = (ull*)d_ws;                      // 2*16*512 = 16384 ull
  ull*   r_rep  = (ull*)((char*)d_ws + 131072);    // 8 rep x 2 par x 640 ull
  ull*   h_okr  = (ull*)((char*)d_ws + 212992);    // 8 rep x 2 par x 16 ull
  ull*   r_flag = (ull*)((char*)d_ws + 215040);    // 8 rep x 2 par x 16 ull

  hipMemsetAsync(d_ws, 0, 217088, stream);         // tags=0 != any want (1..1024)
  hipLaunchKernelGGL(ntm_kernel, dim3(NWG), dim3(NT), 0, stream,
                     xg, h0g, c0g, mem0g, read0g, Wih, bih, Whh, bhh,
                     Wfc, bfc, We, be, Wa, ba, Wk, bk, Wb, bbeta,
                     yout, h_tag, r_rep, h_okr, r_flag);
}

// Round 9
// 6705.857 us; speedup vs baseline: 1.1377x; 1.1377x over previous
//
#include <hip/hip_runtime.h>
#include <math.h>

#define Bq   16
#define Tq   1024
#define OUTq 64
#define Hq   512
#define Nq   128
#define Mq   40
#define NT   512
#define NISL 16        // islands = batches
#define GWG  13        // gate WGs per island (12 x 40 dims + 1 x 32 dims)
#define IWG  14        // WGs per island (GWG + 1 mem)
#define NWG  224       // 8 XCDs x 28; island b on XCD b%8 (blockIdx%8 mapping)
#define EPSq 1e-8f

typedef unsigned long long ull;

__device__ __forceinline__ float sigmf(float x){ return 1.f/(1.f + expf(-x)); }
__device__ __forceinline__ float softplusf(float x){ return (x > 20.f) ? x : log1pf(expf(x)); }

// Agent-scope (IC, cross-XCD correct) tagged word ops — the authoritative path.
__device__ __forceinline__ ull icld64(const ull* p){
  return __hip_atomic_load(p, __ATOMIC_RELAXED, __HIP_MEMORY_SCOPE_AGENT);
}
__device__ __forceinline__ void icst64(ull* p, ull v){
  __hip_atomic_store(p, v, __ATOMIC_RELAXED, __HIP_MEMORY_SCOPE_AGENT);
}
// L2-local fast path: sc0 load bypasses L1 but hits the XCD's L2 (coherent for
// same-XCD producer plain stores, which write through L1 into L2).
__device__ __forceinline__ ull l2ld64(const ull* p){
  ull v;
  asm volatile("global_load_dwordx2 %0, %1, off sc0\n\ts_waitcnt vmcnt(0)"
               : "=v"(v) : "v"(p) : "memory");
  return v;
}
__device__ __forceinline__ ull packtv(unsigned tag, float v){
  return ((ull)tag << 32) | (ull)__float_as_uint(v);
}
__device__ __forceinline__ float lowf(ull v){ return __uint_as_float((unsigned)v); }

// Dual publish: plain store (home-XCD L2, fast) + agent shadow (always correct).
__device__ __forceinline__ void publish(ull* loc, ull* sh, ull v){
  *loc = v;
  icst64(sh, v);
}
// Tag-verified wait: spin local L2 briefly, then agent shadow. A local word with
// the right tag is ALWAYS correct (tag+payload are one atomic 8B word, tags are
// monotone, parity-2 spacing is guarded by the dependency chain).
__device__ __forceinline__ float waitword(const ull* loc, const ull* sh, unsigned want){
  #pragma unroll 1
  for (int i = 0; i < 12; ++i){
    const ull v = l2ld64(loc);
    if ((unsigned)(v >> 32) == want) return lowf(v);
    __builtin_amdgcn_s_sleep(1);
  }
  for (;;){
    const ull v = icld64(sh);
    if ((unsigned)(v >> 32) == want) return lowf(v);
    __builtin_amdgcn_s_sleep(2);
  }
}

extern "C" __global__ void __launch_bounds__(NT, 1)
ntm_kernel(const float* __restrict__ xg,  const float* __restrict__ h0g,
           const float* __restrict__ c0g, const float* __restrict__ mem0g,
           const float* __restrict__ read0g,
           const float* __restrict__ Wih, const float* __restrict__ bih,
           const float* __restrict__ Whh, const float* __restrict__ bhh,
           const float* __restrict__ Wfc, const float* __restrict__ bfc,
           const float* __restrict__ We,  const float* __restrict__ be,
           const float* __restrict__ Wa,  const float* __restrict__ ba,
           const float* __restrict__ Wk,  const float* __restrict__ bk,
           const float* __restrict__ Wb,  const float* __restrict__ bbeta,
           float* __restrict__ yout, ull* __restrict__ rdy,
           ull* __restrict__ h_loc, ull* __restrict__ h_sh,
           ull* __restrict__ r_loc, ull* __restrict__ r_sh)
{
  const int blk = blockIdx.x;
  const int tid = threadIdx.x;
  const int x   = blk & 7;           // XCD under blockIdx%8 round-robin
  const int j   = blk >> 3;          // 0..27 within XCD
  const int bat = (j < IWG) ? x : (x + 8);
  const int slot= (j < IWG) ? j : (j - IWG);
  __shared__ __align__(16) char smem[41344];

  if (slot < GWG){
    // ---- gate WG: island `bat`, h-dims [d0, d0+nd) (all 4 gates) ----
    float* inp_s  = (float*)smem;               // 640 f: x[0,64) h[64,576)
    float* red_s  = (float*)(smem + 2560);      // 160 x 17
    float* rw_s   = (float*)(smem + 13440);     // 160 x 41 (r-slice weights)
    float* r_s    = (float*)(smem + 39680);     // 40
    float* gate_s = (float*)(smem + 39840);     // 160
    float* c_s    = (float*)(smem + 40480);     // 40
    float* bias_s = (float*)(smem + 40640);     // 160

    const int kseg  = tid & 15;       // 36-float k-slice of 576 (x|h)
    const int rslot = tid >> 4;       // 32 row-slots x 5 rows (padded)
    const int nd    = (slot < 12) ? 40 : 32;
    const int d0    = slot * 40;
    const int rowsR = 4 * nd;         // 160 or 128 real rows

    float4 w4[5][9];
    #pragma unroll
    for (int rr = 0; rr < 5; ++rr){
      const int row = rslot*5 + rr;
      if (row < rowsR){
        const int gate = row / nd, ld = row - gate*nd;
        const int grow = gate*Hq + d0 + ld;
        #pragma unroll
        for (int kk = 0; kk < 9; ++kk){
          float v[4];
          #pragma unroll
          for (int c4 = 0; c4 < 4; ++c4){
            const int k = kseg*36 + kk*4 + c4;
            v[c4] = (k < 64) ? Wih[grow*104 + k] : Whh[grow*512 + (k - 64)];
          }
          w4[rr][kk] = make_float4(v[0], v[1], v[2], v[3]);
        }
      } else {
        #pragma unroll
        for (int kk = 0; kk < 9; ++kk) w4[rr][kk] = make_float4(0.f,0.f,0.f,0.f);
      }
    }
    if (tid < rowsR){
      const int gate = tid / nd, ld = tid - gate*nd;
      const int grow = gate*Hq + d0 + ld;
      bias_s[tid] = bih[grow] + bhh[grow];
    }
    for (int i = tid; i < rowsR*40; i += NT){
      const int row = i / 40, m = i - row*40;
      const int gate = row / nd, ld = row - gate*nd;
      const int grow = gate*Hq + d0 + ld;
      rw_s[row*41 + m] = Wih[grow*104 + 64 + m];
    }
    if (tid < nd) c_s[tid] = c0g[bat*Hq + d0 + tid];
    if (tid < 16)
      *(float4*)&inp_s[tid*4] = ((const float4*)xg)[(bat*Tq + 0)*16 + tid];
    if (tid < 128)
      *(float4*)&inp_s[64 + tid*4] = ((const float4*)h0g)[bat*128 + tid];
    __syncthreads();
    // one-time ready barrier: all 224 WGs resident & warm before timed loop
    if (tid == 0){
      __hip_atomic_fetch_add(rdy, 1ull, __ATOMIC_RELAXED, __HIP_MEMORY_SCOPE_AGENT);
      while (icld64(rdy) < (ull)NWG) __builtin_amdgcn_s_sleep(8);
    }
    __syncthreads();

    for (int t = 0; t < Tq; ++t){
      const int p = t & 1, pm = (t - 1) & 1;
      // main GEMV over x+h (576) — overlaps the island's mem phase
      float acc[5] = {0.f,0.f,0.f,0.f,0.f};
      {
        const float* bp = inp_s + kseg*36;
        #pragma unroll
        for (int kk = 0; kk < 9; ++kk){
          const float4 f = *(const float4*)&bp[kk*4];
          #pragma unroll
          for (int rr = 0; rr < 5; ++rr)
            acc[rr] += w4[rr][kk].x*f.x + w4[rr][kk].y*f.y
                     + w4[rr][kk].z*f.z + w4[rr][kk].w*f.w;
        }
      }
      #pragma unroll
      for (int rr = 0; rr < 5; ++rr)
        red_s[(rslot*5 + rr)*17 + kseg] = acc[rr];
      // r(t-1): island-local hop (t=0: pristine input)
      if (t == 0){
        if (tid < 40) r_s[tid] = read0g[bat*Mq + tid];
      } else if (tid < 40){
        const int idx = (pm*NISL + bat)*Mq + tid;
        r_s[tid] = waitword(&r_loc[idx], &r_sh[idx], (unsigned)t);
      }
      __syncthreads();
      if (tid < rowsR){
        float s2 = bias_s[tid];
        const float* rp = &red_s[tid*17];
        #pragma unroll
        for (int q = 0; q < 16; ++q) s2 += rp[q];
        const float* rwp = &rw_s[tid*41];
        #pragma unroll
        for (int m = 0; m < 40; ++m) s2 += rwp[m]*r_s[m];
        gate_s[tid] = s2;
      }
      __syncthreads();
      if (tid < nd){
        const float gi = gate_s[tid];
        const float gf = gate_s[nd + tid];
        const float gc = gate_s[2*nd + tid];
        const float go = gate_s[3*nd + tid];
        const float iv = sigmf(gi), fv = sigmf(gf), gv = tanhf(gc), ov = sigmf(go);
        const float cn = fv*c_s[tid] + iv*gv;
        const float hn = ov*tanhf(cn);
        c_s[tid] = cn;
        const int idx = (p*NISL + bat)*Hq + d0 + tid;
        publish(&h_loc[idx], &h_sh[idx], packtv((unsigned)(t+1), hn));
        if (t == Tq - 1){
          yout[Bq*Tq*OUTq + bat*Hq + d0 + tid] = hn;             // final h
          yout[Bq*Tq*OUTq + Bq*Hq + bat*Hq + d0 + tid] = cn;     // final c
        }
      }
      // stage full h(t) for next GEMV: one dim per thread, island-local hop
      {
        const int idx = (p*NISL + bat)*Hq + tid;
        inp_s[64 + tid] = waitword(&h_loc[idx], &h_sh[idx], (unsigned)(t+1));
      }
      if (t + 1 < Tq && tid < 16)
        *(float4*)&inp_s[tid*4] = ((const float4*)xg)[(bat*Tq + t + 1)*16 + tid];
      __syncthreads();
    }
  }
  else {
    // ---- mem WG: island `bat` — heads, softmax, memory update, r, out ----
    float* mem_s  = (float*)smem;               // 128 x 44
    float* h_s    = (float*)(smem + 22528);     // 512
    float* hred_s = (float*)(smem + 24576);     // 128 x 4
    float* key_s  = (float*)(smem + 26624);     // 40
    float* e_s    = (float*)(smem + 26784);     // 40
    float* a_s    = (float*)(smem + 26944);     // 40
    float* w_s    = (float*)(smem + 27104);     // 128
    float* rred_s = (float*)(smem + 27616);     // 40 x 9
    float* ored_s = (float*)(smem + 29056);     // 64 x 9

    #pragma unroll
    for (int q = 0; q < 10; ++q){
      const int e = q*512 + tid;
      const int n = e / 40, m = e - n*40;
      mem_s[n*44 + m] = mem0g[bat*(Nq*Mq) + e];
    }
    const int o  = tid & 127;
    const int kc = tid >> 7;
    const float* wrow = (o < 40) ? (Wk + o*Hq)
                      : (o < 80) ? (We + (o-40)*Hq)
                      : (o < 120) ? (Wa + (o-80)*Hq)
                      : (o == 120) ? Wb : nullptr;
    float4 wv2[32];
    if (wrow){
      #pragma unroll
      for (int kk = 0; kk < 32; ++kk)
        wv2[kk] = *(const float4*)&wrow[kc*128 + kk*4];
    } else {
      #pragma unroll
      for (int kk = 0; kk < 32; ++kk) wv2[kk] = make_float4(0.f,0.f,0.f,0.f);
    }
    float4 wfc[16];
    {
      const int o2 = tid & 63, kc8 = tid >> 6;
      #pragma unroll
      for (int kk = 0; kk < 16; ++kk)
        wfc[kk] = *(const float4*)&Wfc[o2*Hq + kc8*64 + kk*4];
    }
    const float bfcv = bfc[tid & 63];
    float hb0 = 0.f, hb1 = 0.f;
    if (tid < 64){
      const int o0 = tid, o1 = tid + 64;
      hb0 = (o0 < 40) ? bk[o0] : be[o0-40];
      hb1 = (o1 < 80) ? be[o1-40] : (o1 < 120) ? ba[o1-80]
          : (o1 == 120) ? bbeta[0] : 0.f;
    }
    __syncthreads();
    if (tid == 0){
      __hip_atomic_fetch_add(rdy, 1ull, __ATOMIC_RELAXED, __HIP_MEMORY_SCOPE_AGENT);
      while (icld64(rdy) < (ull)NWG) __builtin_amdgcn_s_sleep(8);
    }
    __syncthreads();

    for (int t = 0; t < Tq; ++t){
      const int p = t & 1;
      const unsigned want = (unsigned)(t + 1);
      { // acquire h(t): island-local hop, one dim per thread
        const int idx = (p*NISL + bat)*Hq + tid;
        h_s[tid] = waitword(&h_loc[idx], &h_sh[idx], want);
      }
      __syncthreads();                               // M1
      { // heads GEMV: 1 output x 4 k-chunks per thread
        float a0 = 0.f;
        const float* hp = h_s + kc*128;
        #pragma unroll
        for (int kk = 0; kk < 32; ++kk){
          const float4 f = *(const float4*)&hp[kk*4];
          a0 += wv2[kk].x*f.x + wv2[kk].y*f.y + wv2[kk].z*f.z + wv2[kk].w*f.w;
        }
        hred_s[o*4 + kc] = a0;
      }
      __syncthreads();                               // M2
      if (tid < 64){ // wave 0: serial section, shuffle-reduced
        const int l = tid;
        const float4 p0 = *(const float4*)&hred_s[l*4];
        const float4 p1 = *(const float4*)&hred_s[(l+64)*4];
        float s0 = hb0 + p0.x + p0.y + p0.z + p0.w;
        float s1 = hb1 + p1.x + p1.y + p1.z + p1.w;
        float kv = 0.f;
        if (l < 40){ kv = tanhf(s0); key_s[l] = kv; }
        else        { e_s[l-40] = sigmf(s0); }
        if (l < 16)      e_s[l+24]  = sigmf(s1);     // o1 in [64,80)
        else if (l < 56) a_s[l-16]  = tanhf(s1);     // o1 in [80,120)
        float bval = softplusf(s1) + EPSq;           // lane 56: o1==120
        const float bet = __shfl(bval, 56);
        float ss = kv*kv;
        #pragma unroll
        for (int off = 32; off; off >>= 1) ss += __shfl_xor(ss, off);
        const float rinv = 1.f/(sqrtf(ss) + EPSq);
        float sc[2];
        #pragma unroll
        for (int half = 0; half < 2; ++half){
          const int n = l + 64*half;
          float qq = 0.f, dd = 0.f;
          const float* mrow = &mem_s[n*44];
          #pragma unroll
          for (int q = 0; q < 10; ++q){
            const float4 mv = *(const float4*)&mrow[q*4];
            const float4 kvv = *(const float4*)&key_s[q*4];
            qq += mv.x*mv.x + mv.y*mv.y + mv.z*mv.z + mv.w*mv.w;
            dd += mv.x*kvv.x + mv.y*kvv.y + mv.z*kvv.z + mv.w*kvv.w;
          }
          sc[half] = bet * dd * rinv / (sqrtf(qq) + EPSq);
        }
        float mx = fmaxf(sc[0], sc[1]);
        #pragma unroll
        for (int off = 32; off; off >>= 1) mx = fmaxf(mx, __shfl_xor(mx, off));
        const float e0 = expf(sc[0] - mx), e1 = expf(sc[1] - mx);
        float sm = e0 + e1;
        #pragma unroll
        for (int off = 32; off; off >>= 1) sm += __shfl_xor(sm, off);
        const float inv = 1.f/sm;
        w_s[l] = e0*inv; w_s[l+64] = e1*inv;
      }
      __syncthreads();                               // M3
      if (tid < 320){ // fused erase/add update + read partials
        const int m = tid % 40, ng = tid / 40;
        const float ev = e_s[m], av = a_s[m];
        float part = 0.f;
        #pragma unroll
        for (int q = 0; q < 16; ++q){
          const int n = ng*16 + q, idx2 = n*44 + m;
          const float mv = mem_s[idx2];
          const float wn = w_s[n];
          const float nv = fmaf(wn, fmaf(-ev, mv, av), mv);
          mem_s[idx2] = nv;
          part = fmaf(wn, nv, part);
        }
        rred_s[m*9 + ng] = part;
      }
      __syncthreads();                               // M4
      if (tid < 40){
        float r = 0.f;
        #pragma unroll
        for (int q = 0; q < 8; ++q) r += rred_s[tid*9 + q];
        const int idx = (p*NISL + bat)*Mq + tid;
        publish(&r_loc[idx], &r_sh[idx], packtv(want, r));
      }
      { // out(t) = tanh(Wfc h + bfc): off critical path, after r publish
        const int o2 = tid & 63, kc8 = tid >> 6;
        float a0 = 0.f;
        const float* hp = h_s + kc8*64;
        #pragma unroll
        for (int kk = 0; kk < 16; ++kk){
          const float4 f = *(const float4*)&hp[kk*4];
          a0 += wfc[kk].x*f.x + wfc[kk].y*f.y + wfc[kk].z*f.z + wfc[kk].w*f.w;
        }
        ored_s[o2*9 + kc8] = a0;
      }
      __syncthreads();                               // M5
      if (tid < 64){
        float s2 = bfcv;
        const float* op = &ored_s[tid*9];
        #pragma unroll
        for (int q = 0; q < 8; ++q) s2 += op[q];
        yout[(bat*Tq + t)*OUTq + tid] = tanhf(s2);
      }
      __syncthreads();                               // M6: h_s reuse guard
    }
  }
}

extern "C" void kernel_launch(void* const* d_in, const int* in_sizes, int n_in,
                              void* d_out, int out_size, void* d_ws, size_t ws_size,
                              hipStream_t stream){
  const float* xg    = (const float*)d_in[0];
  const float* h0g   = (const float*)d_in[1];
  const float* c0g   = (const float*)d_in[2];
  const float* mem0g = (const float*)d_in[3];
  const float* read0g= (const float*)d_in[4];
  const float* Wih   = (const float*)d_in[5];
  const float* bih   = (const float*)d_in[6];
  const float* Whh   = (const float*)d_in[7];
  const float* bhh   = (const float*)d_in[8];
  const float* Wfc   = (const float*)d_in[9];
  const float* bfc   = (const float*)d_in[10];
  const float* We    = (const float*)d_in[11];
  const float* be    = (const float*)d_in[12];
  const float* Wa    = (const float*)d_in[13];
  const float* ba    = (const float*)d_in[14];
  const float* Wk    = (const float*)d_in[15];
  const float* bk    = (const float*)d_in[16];
  const float* Wb    = (const float*)d_in[17];
  const float* bbeta = (const float*)d_in[18];

  float* yout  = (float*)d_out;
  ull*   rdy   = (ull*)d_ws;                         // 1 word
  ull*   h_loc = (ull*)((char*)d_ws + 4096);         // 2x16x512 = 16384 ull
  ull*   h_sh  = (ull*)((char*)d_ws + 135168);       // 16384 ull
  ull*   r_loc = (ull*)((char*)d_ws + 266240);       // 2x16x40 = 1280 ull
  ull*   r_sh  = (ull*)((char*)d_ws + 276480);       // 1280 ull

  hipMemsetAsync(d_ws, 0, 286720, stream);           // tags=0 != any want (1..1024)
  hipLaunchKernelGGL(ntm_kernel, dim3(NWG), dim3(NT), 0, stream,
                     xg, h0g, c0g, mem0g, read0g, Wih, bih, Whh, bhh,
                     Wfc, bfc, We, be, Wa, ba, Wk, bk, Wb, bbeta,
                     yout, rdy, h_loc, h_sh, r_loc, r_sh);
}